// Round 5
// baseline (479.979 us; speedup 1.0000x reference)
//
#include <hip/hip_runtime.h>
#include <cstdint>
#include <cstddef>

#define HIDN 256
#define NHEAD 8
#define HD 32
#define NSEQ 2048
#define QS (0.17677669529663687f * 1.4426950408889634f)   // 1/sqrt(32) * log2(e)

typedef __attribute__((ext_vector_type(8))) short short8;
typedef __attribute__((ext_vector_type(4))) short short4v;
typedef __attribute__((ext_vector_type(4))) float f32x4;

static __device__ __forceinline__ short f2bf(float f) {
    union { float f; uint32_t u; } v; v.f = f;
    uint32_t r = (v.u + 0x7FFF + ((v.u >> 16) & 1)) >> 16;
    return (short)r;
}
static __device__ __forceinline__ float bf2f(short s) {
    union { uint32_t u; float f; } v; v.u = ((uint32_t)(uint16_t)s) << 16;
    return v.f;
}
static __device__ __forceinline__ uint32_t fbits(float f) {
    union { float f; uint32_t u; } v; v.f = f; return v.u;
}

// ---------------------------------------------------------------------------
// Kernel 0: weight conversion (QS folded into Wq, alphas folded into Wg).
// ---------------------------------------------------------------------------
__global__ __launch_bounds__(256) void wcvt_kernel(
    const float* __restrict__ Wq, const float* __restrict__ Wk,
    const float* __restrict__ Wv, const float* __restrict__ Wvec,
    const float* __restrict__ Wo, const float* __restrict__ Wg,
    const float* __restrict__ bq, const float* __restrict__ bk,
    const float* __restrict__ bv,
    const float* __restrict__ ad, const float* __restrict__ an,
    short* __restrict__ Wqkvb, short* __restrict__ Wvecb,
    short* __restrict__ Wob, short* __restrict__ Wgb, float* __restrict__ bqkvs)
{
    int idx = blockIdx.x * 256 + threadIdx.x;
    if (idx < 65536)        Wqkvb[idx] = f2bf(Wq[idx] * QS);
    else if (idx < 131072)  Wqkvb[idx] = f2bf(Wk[idx - 65536]);
    else if (idx < 196608)  Wqkvb[idx] = f2bf(Wv[idx - 131072]);
    else if (idx < 327680)  Wvecb[idx - 196608] = f2bf(Wvec[idx - 196608]);
    else if (idx < 524288)  Wob[idx - 327680] = f2bf(Wo[idx - 327680]);
    else {
        int i2 = idx - 524288;
        int k = i2 & 511;
        float s = (k < 256) ? ad[0] : an[0];
        Wgb[i2] = f2bf(Wg[i2] * s);
    }
    if (idx < 256)          bqkvs[idx] = bq[idx] * QS;
    else if (idx < 512)     bqkvs[idx] = bk[idx - 256];
    else if (idx < 768)     bqkvs[idx] = bv[idx - 512];
}

// ---------------------------------------------------------------------------
// Kernel 1: fused QKV via MFMA. grid 256 (token-tiles of 32). x staged once,
// A-fragments hoisted; y-loop over q/k/v reuses them.
// ---------------------------------------------------------------------------
__global__ __launch_bounds__(256) void qkv_kernel(
    const float* __restrict__ x, const short* __restrict__ Wqkvb,
    const float* __restrict__ bqkvs,
    short* __restrict__ qbf, short* __restrict__ kbf, short* __restrict__ vtb)
{
    __shared__ short xs[32 * 264];
    __shared__ short vtmp[256 * 34];
    const int tid = threadIdx.x;
    const int m0 = blockIdx.x * 32;
    const int b  = m0 >> 11;
    const int n0 = m0 & 2047;

    #pragma unroll
    for (int l = 0; l < 8; l++) {
        int i = l * 256 + tid;
        int t = i >> 6, j4 = i & 63;
        float4 v = *(const float4*)(x + (size_t)(m0 + t) * 1024 + j4 * 4);
        short4v s = { f2bf(v.x), f2bf(v.y), f2bf(v.z), f2bf(v.w) };
        *(short4v*)&xs[t * 264 + j4 * 4] = s;
    }
    __syncthreads();

    const int wave = tid >> 6, lane = tid & 63;
    const int col = lane & 15, quad = lane >> 4;

    // hoist A-fragments (2 m-tiles x 8 k-steps)
    short8 xf[2][8];
    #pragma unroll
    for (int mt = 0; mt < 2; mt++)
        #pragma unroll
        for (int kk = 0; kk < 8; kk++)
            xf[mt][kk] = *(const short8*)&xs[(mt * 16 + col) * 264 + kk * 32 + quad * 8];

    #pragma unroll
    for (int y = 0; y < 3; y++) {
        f32x4 acc[2][4];
        #pragma unroll
        for (int mt = 0; mt < 2; mt++)
            #pragma unroll
            for (int nt = 0; nt < 4; nt++) acc[mt][nt] = (f32x4){0.f,0.f,0.f,0.f};

        const short* Wb = Wqkvb + (size_t)(y * 256 + wave * 64) * 256;
        #pragma unroll
        for (int kk = 0; kk < 8; kk++) {
            #pragma unroll
            for (int nt = 0; nt < 4; nt++) {
                short8 wf = *(const short8*)(Wb + (size_t)(nt * 16 + col) * 256 + kk * 32 + quad * 8);
                #pragma unroll
                for (int mt = 0; mt < 2; mt++)
                    acc[mt][nt] = __builtin_amdgcn_mfma_f32_16x16x32_bf16(wf, xf[mt][kk], acc[mt][nt], 0, 0, 0);
            }
        }

        if (y < 2) {
            short* dst = (y == 0) ? qbf : kbf;
            #pragma unroll
            for (int nt = 0; nt < 4; nt++) {
                int ch = wave * 64 + nt * 16 + quad * 4;
                float4 bi = *(const float4*)&bqkvs[y * 256 + ch];
                int h = ch >> 5, d = ch & 31;
                #pragma unroll
                for (int mt = 0; mt < 2; mt++) {
                    int n = n0 + mt * 16 + col;
                    short4v s = { f2bf(acc[mt][nt][0] + bi.x), f2bf(acc[mt][nt][1] + bi.y),
                                  f2bf(acc[mt][nt][2] + bi.z), f2bf(acc[mt][nt][3] + bi.w) };
                    *(short4v*)(dst + ((size_t)(b * 8 + h) * 2048 + n) * 32 + d) = s;
                }
            }
        } else {
            #pragma unroll
            for (int nt = 0; nt < 4; nt++) {
                int ch = wave * 64 + nt * 16 + quad * 4;
                float4 bi = *(const float4*)&bqkvs[512 + ch];
                #pragma unroll
                for (int mt = 0; mt < 2; mt++) {
                    int tok = mt * 16 + col;
                    vtmp[(ch + 0) * 34 + tok] = f2bf(acc[mt][nt][0] + bi.x);
                    vtmp[(ch + 1) * 34 + tok] = f2bf(acc[mt][nt][1] + bi.y);
                    vtmp[(ch + 2) * 34 + tok] = f2bf(acc[mt][nt][2] + bi.z);
                    vtmp[(ch + 3) * 34 + tok] = f2bf(acc[mt][nt][3] + bi.w);
                }
            }
        }
    }
    __syncthreads();
    {
        int ch = tid;
        short s[32];
        #pragma unroll
        for (int t = 0; t < 32; t++) s[t] = vtmp[ch * 34 + t];
        size_t row = ((size_t)(b * 8 + (ch >> 5)) * 128 + (ch & 31)) * 2048 + n0;
        #pragma unroll
        for (int g = 0; g < 4; g++)
            *(short8*)(vtb + row + g * 8) = *(short8*)&s[g * 8];
    }
}

// ---------------------------------------------------------------------------
// Kernel 2: fused vec_dot (MFMA) + vec_norm + V^T vec-rows. grid 512 x 512.
// ---------------------------------------------------------------------------
__global__ __launch_bounds__(512) void vec_kernel(
    const float* __restrict__ x, const short* __restrict__ Wvecb,
    float* __restrict__ dotb, short* __restrict__ invb,
    float* __restrict__ normb, short* __restrict__ vtb)
{
    __shared__ short vb[3 * 16 * 264];
    const int tid = threadIdx.x;
    const int m0 = blockIdx.x * 16;
    const int b = m0 >> 11, n0 = m0 & 2047;

    #pragma unroll
    for (int p = 0; p < 6; p++) {
        int f4 = p * 512 + tid;
        int t = f4 / 192;
        int rem = f4 - t * 192;
        int c = rem >> 6, j4 = rem & 63;
        float4 v = *(const float4*)(x + (size_t)(m0 + t) * 1024 + 256 + c * 256 + j4 * 4);
        short4v s = { f2bf(v.x), f2bf(v.y), f2bf(v.z), f2bf(v.w) };
        *(short4v*)&vb[(c * 16 + t) * 264 + j4 * 4] = s;
    }
    __syncthreads();

    const int wave = tid >> 6, lane = tid & 63;
    const int col = lane & 15, quad = lane >> 4;
    const int j0 = wave * 32;

    f32x4 dac[2] = {(f32x4){0.f,0.f,0.f,0.f}, (f32x4){0.f,0.f,0.f,0.f}};
    #pragma unroll
    for (int c = 0; c < 3; c++) {
        f32x4 d1[2] = {(f32x4){0.f,0.f,0.f,0.f}, (f32x4){0.f,0.f,0.f,0.f}};
        f32x4 d2[2] = {(f32x4){0.f,0.f,0.f,0.f}, (f32x4){0.f,0.f,0.f,0.f}};
        #pragma unroll
        for (int kk = 0; kk < 8; kk++) {
            short8 xf = *(const short8*)&vb[(c * 16 + col) * 264 + kk * 32 + quad * 8];
            #pragma unroll
            for (int nt = 0; nt < 2; nt++) {
                short8 w1 = *(const short8*)&Wvecb[(size_t)(j0 + nt * 16 + col) * 256 + kk * 32 + quad * 8];
                short8 w2 = *(const short8*)&Wvecb[(size_t)(256 + j0 + nt * 16 + col) * 256 + kk * 32 + quad * 8];
                d1[nt] = __builtin_amdgcn_mfma_f32_16x16x32_bf16(w1, xf, d1[nt], 0, 0, 0);
                d2[nt] = __builtin_amdgcn_mfma_f32_16x16x32_bf16(w2, xf, d2[nt], 0, 0, 0);
            }
        }
        #pragma unroll
        for (int nt = 0; nt < 2; nt++) dac[nt] += d1[nt] * d2[nt];
    }
    #pragma unroll
    for (int nt = 0; nt < 2; nt++) {
        float4 o = { dac[nt][0], dac[nt][1], dac[nt][2], dac[nt][3] };
        *(float4*)&dotb[(size_t)(m0 + col) * 256 + j0 + nt * 16 + quad * 4] = o;
        short4v s = { f2bf(dac[nt][0]), f2bf(dac[nt][1]), f2bf(dac[nt][2]), f2bf(dac[nt][3]) };
        *(short4v*)&invb[(size_t)(m0 + col) * 512 + j0 + nt * 16 + quad * 4] = s;
    }

    // norm + V^T vec rows (from bf16 staged values; rel err ~2^-9, negligible)
    const int j = tid & 255, tp = tid >> 8;
    const int h = j >> 5, d = j & 31;
    #pragma unroll
    for (int t8 = 0; t8 < 8; t8++) {
        int t = tp * 8 + t8;
        float v0 = bf2f(vb[(0 * 16 + t) * 264 + j]);
        float v1 = bf2f(vb[(1 * 16 + t) * 264 + j]);
        float v2 = bf2f(vb[(2 * 16 + t) * 264 + j]);
        float nm = sqrtf(v0 * v0 + v1 * v1 + v2 * v2);
        normb[(size_t)(m0 + t) * 256 + j] = nm;
        invb[(size_t)(m0 + t) * 512 + 256 + j] = f2bf(nm);
    }
    #pragma unroll
    for (int c = 0; c < 3; c++) {
        short8 s;
        #pragma unroll
        for (int t8 = 0; t8 < 8; t8++) s[t8] = vb[(c * 16 + tp * 8 + t8) * 264 + j];
        size_t row = ((size_t)(b * 8 + h) * 128 + 32 + c * 32 + d) * 2048 + n0 + tp * 8;
        *(short8*)(vtb + row) = s;
    }
}

// ---------------------------------------------------------------------------
// Kernel 3: MFMA flash attention, no-max softmax (shift-invariant; scores
// bounded ~|1| in exp2 domain), no K/V LDS staging (global/L1 direct),
// no __syncthreads. grid 1024 (bh x 32 q-tiles of 64), block 256.
// ---------------------------------------------------------------------------
__global__ __launch_bounds__(256) void attn_kernel(
    const short* __restrict__ qb, const short* __restrict__ kb,
    const short* __restrict__ vtb,
    short* __restrict__ xob, short* __restrict__ ovb)
{
    __shared__ short Pl[4][16 * 72];   // 9.2 KB, stride 36 words: conflict-free b128
    const int tid = threadIdx.x;
    const int wave = tid >> 6, lane = tid & 63;
    const int col = lane & 15, quad = lane >> 4;
    const int bh = blockIdx.x >> 5, qt = blockIdx.x & 31;
    const int m0 = qt * 64 + wave * 16;
    const int b = bh >> 3, h = bh & 7;

    const short* qbase = qb + (size_t)bh * NSEQ * HD;
    const short* kbase = kb + (size_t)bh * NSEQ * HD;
    const short* vbase = vtb + (size_t)bh * 128 * NSEQ;

    short8 qfrag = *(const short8*)(qbase + (size_t)(m0 + col) * 32 + quad * 8);

    f32x4 o[8];
    #pragma unroll
    for (int dt = 0; dt < 8; dt++) o[dt] = (f32x4){0.f,0.f,0.f,0.f};
    float lrun = 0.f;

    for (int kt = 0; kt < 32; kt++) {
        const short* kt0 = kbase + (size_t)kt * 64 * 32;
        short8 kf[4];
        #pragma unroll
        for (int nt = 0; nt < 4; nt++)
            kf[nt] = *(const short8*)(kt0 + (size_t)(nt * 16 + col) * 32 + quad * 8);

        f32x4 sc[4];
        #pragma unroll
        for (int nt = 0; nt < 4; nt++)
            sc[nt] = __builtin_amdgcn_mfma_f32_16x16x32_bf16(
                kf[nt], qfrag, (f32x4){0.f,0.f,0.f,0.f}, 0, 0, 0);

        float rs = 0.f;
        short* pd = &Pl[wave][col * 72];
        #pragma unroll
        for (int nt = 0; nt < 4; nt++) {
            float p0 = exp2f(sc[nt][0]), p1 = exp2f(sc[nt][1]);
            float p2 = exp2f(sc[nt][2]), p3 = exp2f(sc[nt][3]);
            rs += (p0 + p1) + (p2 + p3);
            uint32_t w0 = (fbits(p0) + 0x8000u) >> 16 | ((fbits(p1) + 0x8000u) & 0xFFFF0000u);
            uint32_t w1 = (fbits(p2) + 0x8000u) >> 16 | ((fbits(p3) + 0x8000u) & 0xFFFF0000u);
            uint2 w = { w0, w1 };
            *(uint2*)(pd + nt * 16 + quad * 4) = w;
        }
        lrun += rs;

        #pragma unroll
        for (int c = 0; c < 2; c++) {
            short8 pa = *(const short8*)&Pl[wave][col * 72 + c * 32 + quad * 8];
            #pragma unroll
            for (int dt = 0; dt < 8; dt++) {
                short8 vf = *(const short8*)(vbase + (size_t)(dt * 16 + col) * NSEQ + kt * 64 + c * 32 + quad * 8);
                o[dt] = __builtin_amdgcn_mfma_f32_16x16x32_bf16(vf, pa, o[dt], 0, 0, 0);
            }
        }
    }

    float l = lrun;
    l += __shfl_xor(l, 16);
    l += __shfl_xor(l, 32);
    float linv = 1.0f / l;

    size_t mg = (size_t)b * 2048 + m0 + col;
    short* xr = xob + mg * 256 + h * 32;
    #pragma unroll
    for (int dt = 0; dt < 2; dt++) {
        short4v sv = { f2bf(o[dt][0] * linv), f2bf(o[dt][1] * linv),
                       f2bf(o[dt][2] * linv), f2bf(o[dt][3] * linv) };
        *(short4v*)(xr + dt * 16 + quad * 4) = sv;
    }
    short* vr = ovb + mg * 768 + h * 32;
    #pragma unroll
    for (int dt = 2; dt < 8; dt++) {
        int c = (dt - 2) >> 1, d2 = ((dt - 2) & 1) * 16 + quad * 4;
        short4v sv = { f2bf(o[dt][0] * linv), f2bf(o[dt][1] * linv),
                       f2bf(o[dt][2] * linv), f2bf(o[dt][3] * linv) };
        *(short4v*)(vr + c * 256 + d2) = sv;
    }
}

// ---------------------------------------------------------------------------
// Kernel 4: MFMA epilogue GEMM + fused combine. grid 512, block 256.
// ---------------------------------------------------------------------------
__global__ __launch_bounds__(256) void ogemm_kernel(
    const float* __restrict__ x, const short* __restrict__ xob,
    const short* __restrict__ invb,
    const float* __restrict__ dotb, const float* __restrict__ normb,
    const short* __restrict__ ovb,
    const short* __restrict__ Wob, const short* __restrict__ Wgb,
    const float* __restrict__ bo, const float* __restrict__ bg,
    float* __restrict__ out)
{
    __shared__ __align__(16) union {
        struct { short inv[16 * 520]; short xo[16 * 264]; } in;
        struct { short gate[16 * 264]; short o[16 * 776]; } ob;
    } u;
    const int tid = threadIdx.x;
    const int M0 = blockIdx.x * 16;

    #pragma unroll
    for (int l = 0; l < 4; l++) {
        int i = l * 256 + tid;
        int m = i >> 6, seg = i & 63;
        *(short8*)&u.in.inv[m * 520 + seg * 8] =
            *(const short8*)(invb + (size_t)(M0 + m) * 512 + seg * 8);
    }
    #pragma unroll
    for (int l = 0; l < 2; l++) {
        int i = l * 256 + tid;
        int m = i >> 5, seg = i & 31;
        *(short8*)&u.in.xo[m * 264 + seg * 8] =
            *(const short8*)(xob + (size_t)(M0 + m) * 256 + seg * 8);
    }
    __syncthreads();

    const int wave = tid >> 6, lane = tid & 63;
    const int col = lane & 15, quad = lane >> 4;

    f32x4 acc[16];
    #pragma unroll
    for (int nt = 0; nt < 16; nt++) acc[nt] = (f32x4){0.f,0.f,0.f,0.f};

    if (wave == 0) {
        #pragma unroll
        for (int kk = 0; kk < 16; kk++) {
            short8 xf = *(const short8*)&u.in.inv[col * 520 + kk * 32 + quad * 8];
            #pragma unroll
            for (int nt = 0; nt < 16; nt++) {
                short8 wf = *(const short8*)(Wgb + (size_t)(nt * 16 + col) * 512 + kk * 32 + quad * 8);
                acc[nt] = __builtin_amdgcn_mfma_f32_16x16x32_bf16(wf, xf, acc[nt], 0, 0, 0);
            }
        }
    } else {
        const short* Wb = Wob + (size_t)(wave - 1) * 256 * 256;
        #pragma unroll
        for (int kk = 0; kk < 8; kk++) {
            short8 xf = *(const short8*)&u.in.xo[col * 264 + kk * 32 + quad * 8];
            #pragma unroll
            for (int nt = 0; nt < 16; nt++) {
                short8 wf = *(const short8*)(Wb + (size_t)(nt * 16 + col) * 256 + kk * 32 + quad * 8);
                acc[nt] = __builtin_amdgcn_mfma_f32_16x16x32_bf16(wf, xf, acc[nt], 0, 0, 0);
            }
        }
    }
    __syncthreads();

    if (wave == 0) {
        #pragma unroll
        for (int nt = 0; nt < 16; nt++) {
            int ch = nt * 16 + quad * 4;
            float4 bi = *(const float4*)&bg[ch];
            short4v s = { f2bf(1.f / (1.f + __expf(-(acc[nt][0] + bi.x)))),
                          f2bf(1.f / (1.f + __expf(-(acc[nt][1] + bi.y)))),
                          f2bf(1.f / (1.f + __expf(-(acc[nt][2] + bi.z)))),
                          f2bf(1.f / (1.f + __expf(-(acc[nt][3] + bi.w)))) };
            *(short4v*)&u.ob.gate[col * 264 + ch] = s;
        }
    } else {
        #pragma unroll
        for (int nt = 0; nt < 16; nt++) {
            int ch = (wave - 1) * 256 + nt * 16 + quad * 4;
            float4 bi = *(const float4*)&bo[ch];
            short4v s = { f2bf(acc[nt][0] + bi.x), f2bf(acc[nt][1] + bi.y),
                          f2bf(acc[nt][2] + bi.z), f2bf(acc[nt][3] + bi.w) };
            *(short4v*)&u.ob.o[col * 776 + ch] = s;
        }
    }
    __syncthreads();

    #pragma unroll
    for (int l = 0; l < 16; l++) {
        int idx4 = l * 256 + tid;
        int m = idx4 >> 8;
        int j = (idx4 & 255) * 4;
        size_t mg = (size_t)(M0 + m);
        if (j < 256) {
            float4 dv = *(const float4*)(dotb + mg * 256 + j);
            float4 nv = *(const float4*)(normb + mg * 256 + j);
            short4v o1 = *(short4v*)&u.ob.o[m * 776 + j];
            short4v o2 = *(short4v*)&u.ob.o[m * 776 + 256 + j];
            short4v o3 = *(short4v*)&u.ob.o[m * 776 + 512 + j];
            float4 r;
            r.x = dv.x * bf2f(o1[0]) + nv.x * bf2f(o2[0]) + bf2f(o3[0]);
            r.y = dv.y * bf2f(o1[1]) + nv.y * bf2f(o2[1]) + bf2f(o3[1]);
            r.z = dv.z * bf2f(o1[2]) + nv.z * bf2f(o2[2]) + bf2f(o3[2]);
            r.w = dv.w * bf2f(o1[3]) + nv.w * bf2f(o2[3]) + bf2f(o3[3]);
            *(float4*)(out + mg * 1024 + j) = r;
        } else {
            int c = (j >> 8) - 1, jj = j & 255;
            short4v g4 = *(short4v*)&u.ob.gate[m * 264 + jj];
            short4v av4 = *(const short4v*)(ovb + mg * 768 + c * 256 + jj);
            float4 xv = *(const float4*)(x + mg * 1024 + 256 + c * 256 + jj);
            float4 r = { bf2f(g4[0]) * bf2f(av4[0]) + xv.x, bf2f(g4[1]) * bf2f(av4[1]) + xv.y,
                         bf2f(g4[2]) * bf2f(av4[2]) + xv.z, bf2f(g4[3]) * bf2f(av4[3]) + xv.w };
            *(float4*)(out + mg * 1024 + j) = r;
        }
    }
}

// ---------------------------------------------------------------------------
extern "C" void kernel_launch(void* const* d_in, const int* in_sizes, int n_in,
                              void* d_out, int out_size, void* d_ws, size_t ws_size,
                              hipStream_t stream)
{
    const float* x    = (const float*)d_in[0];
    const float* Wq   = (const float*)d_in[1];
    const float* bq   = (const float*)d_in[2];
    const float* Wk   = (const float*)d_in[3];
    const float* bk   = (const float*)d_in[4];
    const float* Wv   = (const float*)d_in[5];
    const float* bv   = (const float*)d_in[6];
    const float* Wvec = (const float*)d_in[7];
    const float* Wo   = (const float*)d_in[8];
    const float* bo   = (const float*)d_in[9];
    const float* Wg   = (const float*)d_in[10];
    const float* bg   = (const float*)d_in[11];
    const float* adp  = (const float*)d_in[12];
    const float* anp  = (const float*)d_in[13];
    float* out = (float*)d_out;

    float* ws    = (float*)d_ws;
    short* qbf   = (short*)ws;                 // 2,097,152 bf16
    short* kbf   = (short*)(ws + 1048576);
    short* vtb   = (short*)(ws + 2097152);     // 8,388,608 bf16
    float* dotb  = ws + 6291456;
    float* normb = ws + 8388608;
    short* xob   = (short*)(ws + 10485760);    // 2,097,152 bf16
    short* ovb   = (short*)(ws + 11534336);    // 6,291,456 bf16 (fits old region)
    short* invb  = (short*)(ws + 17825792);    // 4,194,304 bf16
    short* Wqkvb = (short*)(ws + 19922944);
    float* bqkvs = ws + 20021248;
    short* Wvecb = (short*)(ws + 20022016);
    short* Wob   = (short*)(ws + 20087552);
    short* Wgb   = (short*)(ws + 20185856);

    wcvt_kernel<<<2560, 256, 0, stream>>>(Wq, Wk, Wv, Wvec, Wo, Wg, bq, bk, bv,
                                          adp, anp, Wqkvb, Wvecb, Wob, Wgb, bqkvs);
    qkv_kernel<<<256, 256, 0, stream>>>(x, Wqkvb, bqkvs, qbf, kbf, vtb);
    vec_kernel<<<512, 512, 0, stream>>>(x, Wvecb, dotb, invb, normb, vtb);
    attn_kernel<<<1024, 256, 0, stream>>>(qbf, kbf, vtb, xob, ovb);
    ogemm_kernel<<<512, 256, 0, stream>>>(x, xob, invb, dotb, normb, ovb,
                                          Wob, Wgb, bo, bg, out);
}

// Round 6
// 323.147 us; speedup vs baseline: 1.4853x; 1.4853x over previous
//
#include <hip/hip_runtime.h>
#include <cstdint>
#include <cstddef>

#define HIDN 256
#define NHEAD 8
#define HD 32
#define NSEQ 2048
#define QS (0.17677669529663687f * 1.4426950408889634f)   // 1/sqrt(32) * log2(e)

typedef __attribute__((ext_vector_type(8))) short short8;
typedef __attribute__((ext_vector_type(4))) short short4v;
typedef __attribute__((ext_vector_type(4))) float f32x4;

static __device__ __forceinline__ short f2bf(float f) {
    union { float f; uint32_t u; } v; v.f = f;
    uint32_t r = (v.u + 0x7FFF + ((v.u >> 16) & 1)) >> 16;
    return (short)r;
}
static __device__ __forceinline__ float bf2f(short s) {
    union { uint32_t u; float f; } v; v.u = ((uint32_t)(uint16_t)s) << 16;
    return v.f;
}
static __device__ __forceinline__ uint32_t fbits(float f) {
    union { float f; uint32_t u; } v; v.f = f; return v.u;
}

// ---------------------------------------------------------------------------
// Kernel 0: weight conversion (QS folded into Wq, alphas folded into Wg).
// ---------------------------------------------------------------------------
__global__ __launch_bounds__(256) void wcvt_kernel(
    const float* __restrict__ Wq, const float* __restrict__ Wk,
    const float* __restrict__ Wv, const float* __restrict__ Wvec,
    const float* __restrict__ Wo, const float* __restrict__ Wg,
    const float* __restrict__ bq, const float* __restrict__ bk,
    const float* __restrict__ bv,
    const float* __restrict__ ad, const float* __restrict__ an,
    short* __restrict__ Wqkvb, short* __restrict__ Wvecb,
    short* __restrict__ Wob, short* __restrict__ Wgb, float* __restrict__ bqkvs)
{
    int idx = blockIdx.x * 256 + threadIdx.x;
    if (idx < 65536)        Wqkvb[idx] = f2bf(Wq[idx] * QS);
    else if (idx < 131072)  Wqkvb[idx] = f2bf(Wk[idx - 65536]);
    else if (idx < 196608)  Wqkvb[idx] = f2bf(Wv[idx - 131072]);
    else if (idx < 327680)  Wvecb[idx - 196608] = f2bf(Wvec[idx - 196608]);
    else if (idx < 524288)  Wob[idx - 327680] = f2bf(Wo[idx - 327680]);
    else {
        int i2 = idx - 524288;
        int k = i2 & 511;
        float s = (k < 256) ? ad[0] : an[0];
        Wgb[i2] = f2bf(Wg[i2] * s);
    }
    if (idx < 256)          bqkvs[idx] = bq[idx] * QS;
    else if (idx < 512)     bqkvs[idx] = bk[idx - 256];
    else if (idx < 768)     bqkvs[idx] = bv[idx - 512];
}

// ---------------------------------------------------------------------------
// Kernel 1: fused QKV via MFMA. grid 256 (token-tiles of 32).
// ---------------------------------------------------------------------------
__global__ __launch_bounds__(256) void qkv_kernel(
    const float* __restrict__ x, const short* __restrict__ Wqkvb,
    const float* __restrict__ bqkvs,
    short* __restrict__ qbf, short* __restrict__ kbf, short* __restrict__ vtb)
{
    __shared__ short xs[32 * 264];
    __shared__ short vtmp[256 * 34];
    const int tid = threadIdx.x;
    const int m0 = blockIdx.x * 32;
    const int b  = m0 >> 11;
    const int n0 = m0 & 2047;

    #pragma unroll
    for (int l = 0; l < 8; l++) {
        int i = l * 256 + tid;
        int t = i >> 6, j4 = i & 63;
        float4 v = *(const float4*)(x + (size_t)(m0 + t) * 1024 + j4 * 4);
        short4v s = { f2bf(v.x), f2bf(v.y), f2bf(v.z), f2bf(v.w) };
        *(short4v*)&xs[t * 264 + j4 * 4] = s;
    }
    __syncthreads();

    const int wave = tid >> 6, lane = tid & 63;
    const int col = lane & 15, quad = lane >> 4;

    short8 xf[2][8];
    #pragma unroll
    for (int mt = 0; mt < 2; mt++)
        #pragma unroll
        for (int kk = 0; kk < 8; kk++)
            xf[mt][kk] = *(const short8*)&xs[(mt * 16 + col) * 264 + kk * 32 + quad * 8];

    #pragma unroll
    for (int y = 0; y < 3; y++) {
        f32x4 acc[2][4];
        #pragma unroll
        for (int mt = 0; mt < 2; mt++)
            #pragma unroll
            for (int nt = 0; nt < 4; nt++) acc[mt][nt] = (f32x4){0.f,0.f,0.f,0.f};

        const short* Wb = Wqkvb + (size_t)(y * 256 + wave * 64) * 256;
        #pragma unroll
        for (int kk = 0; kk < 8; kk++) {
            #pragma unroll
            for (int nt = 0; nt < 4; nt++) {
                short8 wf = *(const short8*)(Wb + (size_t)(nt * 16 + col) * 256 + kk * 32 + quad * 8);
                #pragma unroll
                for (int mt = 0; mt < 2; mt++)
                    acc[mt][nt] = __builtin_amdgcn_mfma_f32_16x16x32_bf16(wf, xf[mt][kk], acc[mt][nt], 0, 0, 0);
            }
        }

        if (y < 2) {
            short* dst = (y == 0) ? qbf : kbf;
            #pragma unroll
            for (int nt = 0; nt < 4; nt++) {
                int ch = wave * 64 + nt * 16 + quad * 4;
                float4 bi = *(const float4*)&bqkvs[y * 256 + ch];
                int h = ch >> 5, d = ch & 31;
                #pragma unroll
                for (int mt = 0; mt < 2; mt++) {
                    int n = n0 + mt * 16 + col;
                    short4v s = { f2bf(acc[mt][nt][0] + bi.x), f2bf(acc[mt][nt][1] + bi.y),
                                  f2bf(acc[mt][nt][2] + bi.z), f2bf(acc[mt][nt][3] + bi.w) };
                    *(short4v*)(dst + ((size_t)(b * 8 + h) * 2048 + n) * 32 + d) = s;
                }
            }
        } else {
            #pragma unroll
            for (int nt = 0; nt < 4; nt++) {
                int ch = wave * 64 + nt * 16 + quad * 4;
                float4 bi = *(const float4*)&bqkvs[512 + ch];
                #pragma unroll
                for (int mt = 0; mt < 2; mt++) {
                    int tok = mt * 16 + col;
                    vtmp[(ch + 0) * 34 + tok] = f2bf(acc[mt][nt][0] + bi.x);
                    vtmp[(ch + 1) * 34 + tok] = f2bf(acc[mt][nt][1] + bi.y);
                    vtmp[(ch + 2) * 34 + tok] = f2bf(acc[mt][nt][2] + bi.z);
                    vtmp[(ch + 3) * 34 + tok] = f2bf(acc[mt][nt][3] + bi.w);
                }
            }
        }
    }
    __syncthreads();
    {
        int ch = tid;
        short s[32];
        #pragma unroll
        for (int t = 0; t < 32; t++) s[t] = vtmp[ch * 34 + t];
        size_t row = ((size_t)(b * 8 + (ch >> 5)) * 128 + (ch & 31)) * 2048 + n0;
        #pragma unroll
        for (int g = 0; g < 4; g++)
            *(short8*)(vtb + row + g * 8) = *(short8*)&s[g * 8];
    }
}

// ---------------------------------------------------------------------------
// Kernel 2: fused vec_dot (MFMA) + vec_norm + V^T vec-rows. grid 512 x 512.
// ---------------------------------------------------------------------------
__global__ __launch_bounds__(512) void vec_kernel(
    const float* __restrict__ x, const short* __restrict__ Wvecb,
    float* __restrict__ dotb, short* __restrict__ invb,
    float* __restrict__ normb, short* __restrict__ vtb)
{
    __shared__ short vb[3 * 16 * 264];
    const int tid = threadIdx.x;
    const int m0 = blockIdx.x * 16;
    const int b = m0 >> 11, n0 = m0 & 2047;

    #pragma unroll
    for (int p = 0; p < 6; p++) {
        int f4 = p * 512 + tid;
        int t = f4 / 192;
        int rem = f4 - t * 192;
        int c = rem >> 6, j4 = rem & 63;
        float4 v = *(const float4*)(x + (size_t)(m0 + t) * 1024 + 256 + c * 256 + j4 * 4);
        short4v s = { f2bf(v.x), f2bf(v.y), f2bf(v.z), f2bf(v.w) };
        *(short4v*)&vb[(c * 16 + t) * 264 + j4 * 4] = s;
    }
    __syncthreads();

    const int wave = tid >> 6, lane = tid & 63;
    const int col = lane & 15, quad = lane >> 4;
    const int j0 = wave * 32;

    f32x4 dac[2] = {(f32x4){0.f,0.f,0.f,0.f}, (f32x4){0.f,0.f,0.f,0.f}};
    #pragma unroll
    for (int c = 0; c < 3; c++) {
        f32x4 d1[2] = {(f32x4){0.f,0.f,0.f,0.f}, (f32x4){0.f,0.f,0.f,0.f}};
        f32x4 d2[2] = {(f32x4){0.f,0.f,0.f,0.f}, (f32x4){0.f,0.f,0.f,0.f}};
        #pragma unroll
        for (int kk = 0; kk < 8; kk++) {
            short8 xf = *(const short8*)&vb[(c * 16 + col) * 264 + kk * 32 + quad * 8];
            #pragma unroll
            for (int nt = 0; nt < 2; nt++) {
                short8 w1 = *(const short8*)&Wvecb[(size_t)(j0 + nt * 16 + col) * 256 + kk * 32 + quad * 8];
                short8 w2 = *(const short8*)&Wvecb[(size_t)(256 + j0 + nt * 16 + col) * 256 + kk * 32 + quad * 8];
                d1[nt] = __builtin_amdgcn_mfma_f32_16x16x32_bf16(w1, xf, d1[nt], 0, 0, 0);
                d2[nt] = __builtin_amdgcn_mfma_f32_16x16x32_bf16(w2, xf, d2[nt], 0, 0, 0);
            }
        }
        #pragma unroll
        for (int nt = 0; nt < 2; nt++) dac[nt] += d1[nt] * d2[nt];
    }
    #pragma unroll
    for (int nt = 0; nt < 2; nt++) {
        float4 o = { dac[nt][0], dac[nt][1], dac[nt][2], dac[nt][3] };
        *(float4*)&dotb[(size_t)(m0 + col) * 256 + j0 + nt * 16 + quad * 4] = o;
        short4v s = { f2bf(dac[nt][0]), f2bf(dac[nt][1]), f2bf(dac[nt][2]), f2bf(dac[nt][3]) };
        *(short4v*)&invb[(size_t)(m0 + col) * 512 + j0 + nt * 16 + quad * 4] = s;
    }

    const int j = tid & 255, tp = tid >> 8;
    const int h = j >> 5, d = j & 31;
    #pragma unroll
    for (int t8 = 0; t8 < 8; t8++) {
        int t = tp * 8 + t8;
        float v0 = bf2f(vb[(0 * 16 + t) * 264 + j]);
        float v1 = bf2f(vb[(1 * 16 + t) * 264 + j]);
        float v2 = bf2f(vb[(2 * 16 + t) * 264 + j]);
        float nm = sqrtf(v0 * v0 + v1 * v1 + v2 * v2);
        normb[(size_t)(m0 + t) * 256 + j] = nm;
        invb[(size_t)(m0 + t) * 512 + 256 + j] = f2bf(nm);
    }
    #pragma unroll
    for (int c = 0; c < 3; c++) {
        short8 s;
        #pragma unroll
        for (int t8 = 0; t8 < 8; t8++) s[t8] = vb[(c * 16 + tp * 8 + t8) * 264 + j];
        size_t row = ((size_t)(b * 8 + h) * 128 + 32 + c * 32 + d) * 2048 + n0 + tp * 8;
        *(short8*)(vtb + row) = s;
    }
}

// ---------------------------------------------------------------------------
// Kernel 3: MFMA flash attention. no-max softmax (exp2 domain, scores |s|<~2),
// K/V staged in LDS with conflict-optimal strides, per-wave P buffer.
// grid 1024 (bh x 32 q-tiles of 64), block 256 (4 waves x 16 q).
// LDS strides chosen so every b128 access lands on disjoint 4-word spans:
//   K stride 40 shorts (20 words), V stride 72 (36 w), P stride 40 (20 w).
// ---------------------------------------------------------------------------
__global__ __launch_bounds__(256) void attn_kernel(
    const short* __restrict__ qb, const short* __restrict__ kb,
    const short* __restrict__ vtb,
    short* __restrict__ xob, short* __restrict__ ovb)
{
    __shared__ short Ks[64 * 40];       // 5.1 KB
    __shared__ short Vs[128 * 72];      // 18.4 KB
    __shared__ short Pl[4][16 * 40];    // 5.1 KB
    const int tid = threadIdx.x;
    const int wave = tid >> 6, lane = tid & 63;
    const int col = lane & 15, quad = lane >> 4;
    const int bh = blockIdx.x >> 5, qt = blockIdx.x & 31;
    const int m0 = qt * 64 + wave * 16;
    const int b = bh >> 3, h = bh & 7;

    const short* qbase = qb + (size_t)bh * NSEQ * HD;
    const short* kbase = kb + (size_t)bh * NSEQ * HD;
    const short* vbase = vtb + (size_t)bh * 128 * NSEQ;

    short8 qfrag = *(const short8*)(qbase + (size_t)(m0 + col) * 32 + quad * 8);

    f32x4 o[8];
    #pragma unroll
    for (int dt = 0; dt < 8; dt++) o[dt] = (f32x4){0.f,0.f,0.f,0.f};
    float lrun = 0.f;

    const int kr = tid >> 2, kseg = tid & 3;      // K staging: 64 rows x 4 segs
    for (int kt = 0; kt < 32; kt++) {
        __syncthreads();
        *(short8*)&Ks[kr * 40 + kseg * 8] =
            *(const short8*)(kbase + (size_t)(kt * 64 + kr) * 32 + kseg * 8);
        #pragma unroll
        for (int p = 0; p < 4; p++) {             // V staging: 128 rows x 8 segs
            int i = p * 256 + tid;
            int r = i >> 3, seg = i & 7;
            *(short8*)&Vs[r * 72 + seg * 8] =
                *(const short8*)(vbase + (size_t)r * NSEQ + kt * 64 + seg * 8);
        }
        __syncthreads();

        short8 kf[4];
        #pragma unroll
        for (int nt = 0; nt < 4; nt++)
            kf[nt] = *(const short8*)&Ks[(nt * 16 + col) * 40 + quad * 8];

        f32x4 sc[4];
        #pragma unroll
        for (int nt = 0; nt < 4; nt++)
            sc[nt] = __builtin_amdgcn_mfma_f32_16x16x32_bf16(
                kf[nt], qfrag, (f32x4){0.f,0.f,0.f,0.f}, 0, 0, 0);

        float rs = 0.f;
        short* pd = &Pl[wave][col * 40];
        #pragma unroll
        for (int nt = 0; nt < 4; nt++) {
            float p0 = exp2f(sc[nt][0]), p1 = exp2f(sc[nt][1]);
            float p2 = exp2f(sc[nt][2]), p3 = exp2f(sc[nt][3]);
            rs += (p0 + p1) + (p2 + p3);
            // truncation pack (rel err <= 2^-8, cancels after /l)
            uint32_t w0 = (fbits(p0) >> 16) | (fbits(p1) & 0xFFFF0000u);
            uint32_t w1 = (fbits(p2) >> 16) | (fbits(p3) & 0xFFFF0000u);
            uint2 w = { w0, w1 };
            *(uint2*)(pd + nt * 16 + quad * 4) = w;
        }
        lrun += rs;

        #pragma unroll
        for (int c = 0; c < 2; c++) {
            short8 pa = *(const short8*)&Pl[wave][col * 40 + c * 32 + quad * 8];
            #pragma unroll
            for (int dt = 0; dt < 8; dt++) {
                short8 vf = *(const short8*)&Vs[(dt * 16 + col) * 72 + c * 32 + quad * 8];
                o[dt] = __builtin_amdgcn_mfma_f32_16x16x32_bf16(vf, pa, o[dt], 0, 0, 0);
            }
        }
    }

    float l = lrun;
    l += __shfl_xor(l, 16);
    l += __shfl_xor(l, 32);
    float linv = 1.0f / l;

    size_t mg = (size_t)b * 2048 + m0 + col;
    short* xr = xob + mg * 256 + h * 32;
    #pragma unroll
    for (int dt = 0; dt < 2; dt++) {
        short4v sv = { f2bf(o[dt][0] * linv), f2bf(o[dt][1] * linv),
                       f2bf(o[dt][2] * linv), f2bf(o[dt][3] * linv) };
        *(short4v*)(xr + dt * 16 + quad * 4) = sv;
    }
    short* vr = ovb + mg * 768 + h * 32;
    #pragma unroll
    for (int dt = 2; dt < 8; dt++) {
        int c = (dt - 2) >> 1, d2 = ((dt - 2) & 1) * 16 + quad * 4;
        short4v sv = { f2bf(o[dt][0] * linv), f2bf(o[dt][1] * linv),
                       f2bf(o[dt][2] * linv), f2bf(o[dt][3] * linv) };
        *(short4v*)(vr + c * 256 + d2) = sv;
    }
}

// ---------------------------------------------------------------------------
// Kernel 4: MFMA epilogue GEMM + fused combine. grid 512, block 256.
// ---------------------------------------------------------------------------
__global__ __launch_bounds__(256) void ogemm_kernel(
    const float* __restrict__ x, const short* __restrict__ xob,
    const short* __restrict__ invb,
    const float* __restrict__ dotb, const float* __restrict__ normb,
    const short* __restrict__ ovb,
    const short* __restrict__ Wob, const short* __restrict__ Wgb,
    const float* __restrict__ bo, const float* __restrict__ bg,
    float* __restrict__ out)
{
    __shared__ __align__(16) union {
        struct { short inv[16 * 520]; short xo[16 * 264]; } in;
        struct { short gate[16 * 264]; short o[16 * 776]; } ob;
    } u;
    const int tid = threadIdx.x;
    const int M0 = blockIdx.x * 16;

    #pragma unroll
    for (int l = 0; l < 4; l++) {
        int i = l * 256 + tid;
        int m = i >> 6, seg = i & 63;
        *(short8*)&u.in.inv[m * 520 + seg * 8] =
            *(const short8*)(invb + (size_t)(M0 + m) * 512 + seg * 8);
    }
    #pragma unroll
    for (int l = 0; l < 2; l++) {
        int i = l * 256 + tid;
        int m = i >> 5, seg = i & 31;
        *(short8*)&u.in.xo[m * 264 + seg * 8] =
            *(const short8*)(xob + (size_t)(M0 + m) * 256 + seg * 8);
    }
    __syncthreads();

    const int wave = tid >> 6, lane = tid & 63;
    const int col = lane & 15, quad = lane >> 4;

    f32x4 acc[16];
    #pragma unroll
    for (int nt = 0; nt < 16; nt++) acc[nt] = (f32x4){0.f,0.f,0.f,0.f};

    if (wave == 0) {
        #pragma unroll
        for (int kk = 0; kk < 16; kk++) {
            short8 xf = *(const short8*)&u.in.inv[col * 520 + kk * 32 + quad * 8];
            #pragma unroll
            for (int nt = 0; nt < 16; nt++) {
                short8 wf = *(const short8*)(Wgb + (size_t)(nt * 16 + col) * 512 + kk * 32 + quad * 8);
                acc[nt] = __builtin_amdgcn_mfma_f32_16x16x32_bf16(wf, xf, acc[nt], 0, 0, 0);
            }
        }
    } else {
        const short* Wb = Wob + (size_t)(wave - 1) * 256 * 256;
        #pragma unroll
        for (int kk = 0; kk < 8; kk++) {
            short8 xf = *(const short8*)&u.in.xo[col * 264 + kk * 32 + quad * 8];
            #pragma unroll
            for (int nt = 0; nt < 16; nt++) {
                short8 wf = *(const short8*)(Wb + (size_t)(nt * 16 + col) * 256 + kk * 32 + quad * 8);
                acc[nt] = __builtin_amdgcn_mfma_f32_16x16x32_bf16(wf, xf, acc[nt], 0, 0, 0);
            }
        }
    }
    __syncthreads();

    if (wave == 0) {
        #pragma unroll
        for (int nt = 0; nt < 16; nt++) {
            int ch = nt * 16 + quad * 4;
            float4 bi = *(const float4*)&bg[ch];
            short4v s = { f2bf(1.f / (1.f + __expf(-(acc[nt][0] + bi.x)))),
                          f2bf(1.f / (1.f + __expf(-(acc[nt][1] + bi.y)))),
                          f2bf(1.f / (1.f + __expf(-(acc[nt][2] + bi.z)))),
                          f2bf(1.f / (1.f + __expf(-(acc[nt][3] + bi.w)))) };
            *(short4v*)&u.ob.gate[col * 264 + ch] = s;
        }
    } else {
        #pragma unroll
        for (int nt = 0; nt < 16; nt++) {
            int ch = (wave - 1) * 256 + nt * 16 + quad * 4;
            float4 bi = *(const float4*)&bo[ch];
            short4v s = { f2bf(acc[nt][0] + bi.x), f2bf(acc[nt][1] + bi.y),
                          f2bf(acc[nt][2] + bi.z), f2bf(acc[nt][3] + bi.w) };
            *(short4v*)&u.ob.o[col * 776 + ch] = s;
        }
    }
    __syncthreads();

    #pragma unroll
    for (int l = 0; l < 16; l++) {
        int idx4 = l * 256 + tid;
        int m = idx4 >> 8;
        int j = (idx4 & 255) * 4;
        size_t mg = (size_t)(M0 + m);
        if (j < 256) {
            float4 dv = *(const float4*)(dotb + mg * 256 + j);
            float4 nv = *(const float4*)(normb + mg * 256 + j);
            short4v o1 = *(short4v*)&u.ob.o[m * 776 + j];
            short4v o2 = *(short4v*)&u.ob.o[m * 776 + 256 + j];
            short4v o3 = *(short4v*)&u.ob.o[m * 776 + 512 + j];
            float4 r;
            r.x = dv.x * bf2f(o1[0]) + nv.x * bf2f(o2[0]) + bf2f(o3[0]);
            r.y = dv.y * bf2f(o1[1]) + nv.y * bf2f(o2[1]) + bf2f(o3[1]);
            r.z = dv.z * bf2f(o1[2]) + nv.z * bf2f(o2[2]) + bf2f(o3[2]);
            r.w = dv.w * bf2f(o1[3]) + nv.w * bf2f(o2[3]) + bf2f(o3[3]);
            *(float4*)(out + mg * 1024 + j) = r;
        } else {
            int c = (j >> 8) - 1, jj = j & 255;
            short4v g4 = *(short4v*)&u.ob.gate[m * 264 + jj];
            short4v av4 = *(const short4v*)(ovb + mg * 768 + c * 256 + jj);
            float4 xv = *(const float4*)(x + mg * 1024 + 256 + c * 256 + jj);
            float4 r = { bf2f(g4[0]) * bf2f(av4[0]) + xv.x, bf2f(g4[1]) * bf2f(av4[1]) + xv.y,
                         bf2f(g4[2]) * bf2f(av4[2]) + xv.z, bf2f(g4[3]) * bf2f(av4[3]) + xv.w };
            *(float4*)(out + mg * 1024 + j) = r;
        }
    }
}

// ---------------------------------------------------------------------------
extern "C" void kernel_launch(void* const* d_in, const int* in_sizes, int n_in,
                              void* d_out, int out_size, void* d_ws, size_t ws_size,
                              hipStream_t stream)
{
    const float* x    = (const float*)d_in[0];
    const float* Wq   = (const float*)d_in[1];
    const float* bq   = (const float*)d_in[2];
    const float* Wk   = (const float*)d_in[3];
    const float* bk   = (const float*)d_in[4];
    const float* Wv   = (const float*)d_in[5];
    const float* bv   = (const float*)d_in[6];
    const float* Wvec = (const float*)d_in[7];
    const float* Wo   = (const float*)d_in[8];
    const float* bo   = (const float*)d_in[9];
    const float* Wg   = (const float*)d_in[10];
    const float* bg   = (const float*)d_in[11];
    const float* adp  = (const float*)d_in[12];
    const float* anp  = (const float*)d_in[13];
    float* out = (float*)d_out;

    float* ws    = (float*)d_ws;
    short* qbf   = (short*)ws;
    short* kbf   = (short*)(ws + 1048576);
    short* vtb   = (short*)(ws + 2097152);
    float* dotb  = ws + 6291456;
    float* normb = ws + 8388608;
    short* xob   = (short*)(ws + 10485760);
    short* ovb   = (short*)(ws + 11534336);
    short* invb  = (short*)(ws + 17825792);
    short* Wqkvb = (short*)(ws + 19922944);
    float* bqkvs = ws + 20021248;
    short* Wvecb = (short*)(ws + 20022016);
    short* Wob   = (short*)(ws + 20087552);
    short* Wgb   = (short*)(ws + 20185856);

    wcvt_kernel<<<2560, 256, 0, stream>>>(Wq, Wk, Wv, Wvec, Wo, Wg, bq, bk, bv,
                                          adp, anp, Wqkvb, Wvecb, Wob, Wgb, bqkvs);
    qkv_kernel<<<256, 256, 0, stream>>>(x, Wqkvb, bqkvs, qbf, kbf, vtb);
    vec_kernel<<<512, 512, 0, stream>>>(x, Wvecb, dotb, invb, normb, vtb);
    attn_kernel<<<1024, 256, 0, stream>>>(qbf, kbf, vtb, xob, ovb);
    ogemm_kernel<<<512, 256, 0, stream>>>(x, xob, invb, dotb, normb, ovb,
                                          Wob, Wgb, bo, bg, out);
}

// Round 7
// 306.779 us; speedup vs baseline: 1.5646x; 1.0534x over previous
//
#include <hip/hip_runtime.h>
#include <cstdint>
#include <cstddef>

#define HIDN 256
#define NHEAD 8
#define HD 32
#define NSEQ 2048
#define QS (0.17677669529663687f * 1.4426950408889634f)   // 1/sqrt(32) * log2(e)

typedef __attribute__((ext_vector_type(8))) short short8;
typedef __attribute__((ext_vector_type(4))) short short4v;
typedef __attribute__((ext_vector_type(4))) float f32x4;

static __device__ __forceinline__ short f2bf(float f) {
    union { float f; uint32_t u; } v; v.f = f;
    uint32_t r = (v.u + 0x7FFF + ((v.u >> 16) & 1)) >> 16;
    return (short)r;
}
static __device__ __forceinline__ float bf2f(short s) {
    union { uint32_t u; float f; } v; v.u = ((uint32_t)(uint16_t)s) << 16;
    return v.f;
}
static __device__ __forceinline__ uint32_t fbits(float f) {
    union { float f; uint32_t u; } v; v.f = f; return v.u;
}

// ---------------------------------------------------------------------------
// Kernel 0: weight conversion (QS folded into Wq, alphas folded into Wg).
// ---------------------------------------------------------------------------
__global__ __launch_bounds__(256) void wcvt_kernel(
    const float* __restrict__ Wq, const float* __restrict__ Wk,
    const float* __restrict__ Wv, const float* __restrict__ Wvec,
    const float* __restrict__ Wo, const float* __restrict__ Wg,
    const float* __restrict__ bq, const float* __restrict__ bk,
    const float* __restrict__ bv,
    const float* __restrict__ ad, const float* __restrict__ an,
    short* __restrict__ Wqkvb, short* __restrict__ Wvecb,
    short* __restrict__ Wob, short* __restrict__ Wgb, float* __restrict__ bqkvs)
{
    int idx = blockIdx.x * 256 + threadIdx.x;
    if (idx < 65536)        Wqkvb[idx] = f2bf(Wq[idx] * QS);
    else if (idx < 131072)  Wqkvb[idx] = f2bf(Wk[idx - 65536]);
    else if (idx < 196608)  Wqkvb[idx] = f2bf(Wv[idx - 131072]);
    else if (idx < 327680)  Wvecb[idx - 196608] = f2bf(Wvec[idx - 196608]);
    else if (idx < 524288)  Wob[idx - 327680] = f2bf(Wo[idx - 327680]);
    else {
        int i2 = idx - 524288;
        int k = i2 & 511;
        float s = (k < 256) ? ad[0] : an[0];
        Wgb[i2] = f2bf(Wg[i2] * s);
    }
    if (idx < 256)          bqkvs[idx] = bq[idx] * QS;
    else if (idx < 512)     bqkvs[idx] = bk[idx - 256];
    else if (idx < 768)     bqkvs[idx] = bv[idx - 512];
}

// ---------------------------------------------------------------------------
// Kernel 1: fused QKV via MFMA. grid 256 (token-tiles of 32).
// ---------------------------------------------------------------------------
__global__ __launch_bounds__(256) void qkv_kernel(
    const float* __restrict__ x, const short* __restrict__ Wqkvb,
    const float* __restrict__ bqkvs,
    short* __restrict__ qbf, short* __restrict__ kbf, short* __restrict__ vtb)
{
    __shared__ short xs[32 * 264];
    __shared__ short vtmp[256 * 34];
    const int tid = threadIdx.x;
    const int m0 = blockIdx.x * 32;
    const int b  = m0 >> 11;
    const int n0 = m0 & 2047;

    #pragma unroll
    for (int l = 0; l < 8; l++) {
        int i = l * 256 + tid;
        int t = i >> 6, j4 = i & 63;
        float4 v = *(const float4*)(x + (size_t)(m0 + t) * 1024 + j4 * 4);
        short4v s = { f2bf(v.x), f2bf(v.y), f2bf(v.z), f2bf(v.w) };
        *(short4v*)&xs[t * 264 + j4 * 4] = s;
    }
    __syncthreads();

    const int wave = tid >> 6, lane = tid & 63;
    const int col = lane & 15, quad = lane >> 4;

    short8 xf[2][8];
    #pragma unroll
    for (int mt = 0; mt < 2; mt++)
        #pragma unroll
        for (int kk = 0; kk < 8; kk++)
            xf[mt][kk] = *(const short8*)&xs[(mt * 16 + col) * 264 + kk * 32 + quad * 8];

    #pragma unroll
    for (int y = 0; y < 3; y++) {
        f32x4 acc[2][4];
        #pragma unroll
        for (int mt = 0; mt < 2; mt++)
            #pragma unroll
            for (int nt = 0; nt < 4; nt++) acc[mt][nt] = (f32x4){0.f,0.f,0.f,0.f};

        const short* Wb = Wqkvb + (size_t)(y * 256 + wave * 64) * 256;
        #pragma unroll
        for (int kk = 0; kk < 8; kk++) {
            #pragma unroll
            for (int nt = 0; nt < 4; nt++) {
                short8 wf = *(const short8*)(Wb + (size_t)(nt * 16 + col) * 256 + kk * 32 + quad * 8);
                #pragma unroll
                for (int mt = 0; mt < 2; mt++)
                    acc[mt][nt] = __builtin_amdgcn_mfma_f32_16x16x32_bf16(wf, xf[mt][kk], acc[mt][nt], 0, 0, 0);
            }
        }

        if (y < 2) {
            short* dst = (y == 0) ? qbf : kbf;
            #pragma unroll
            for (int nt = 0; nt < 4; nt++) {
                int ch = wave * 64 + nt * 16 + quad * 4;
                float4 bi = *(const float4*)&bqkvs[y * 256 + ch];
                int h = ch >> 5, d = ch & 31;
                #pragma unroll
                for (int mt = 0; mt < 2; mt++) {
                    int n = n0 + mt * 16 + col;
                    short4v s = { f2bf(acc[mt][nt][0] + bi.x), f2bf(acc[mt][nt][1] + bi.y),
                                  f2bf(acc[mt][nt][2] + bi.z), f2bf(acc[mt][nt][3] + bi.w) };
                    *(short4v*)(dst + ((size_t)(b * 8 + h) * 2048 + n) * 32 + d) = s;
                }
            }
        } else {
            #pragma unroll
            for (int nt = 0; nt < 4; nt++) {
                int ch = wave * 64 + nt * 16 + quad * 4;
                float4 bi = *(const float4*)&bqkvs[512 + ch];
                #pragma unroll
                for (int mt = 0; mt < 2; mt++) {
                    int tok = mt * 16 + col;
                    vtmp[(ch + 0) * 34 + tok] = f2bf(acc[mt][nt][0] + bi.x);
                    vtmp[(ch + 1) * 34 + tok] = f2bf(acc[mt][nt][1] + bi.y);
                    vtmp[(ch + 2) * 34 + tok] = f2bf(acc[mt][nt][2] + bi.z);
                    vtmp[(ch + 3) * 34 + tok] = f2bf(acc[mt][nt][3] + bi.w);
                }
            }
        }
    }
    __syncthreads();
    {
        int ch = tid;
        short s[32];
        #pragma unroll
        for (int t = 0; t < 32; t++) s[t] = vtmp[ch * 34 + t];
        size_t row = ((size_t)(b * 8 + (ch >> 5)) * 128 + (ch & 31)) * 2048 + n0;
        #pragma unroll
        for (int g = 0; g < 4; g++)
            *(short8*)(vtb + row + g * 8) = *(short8*)&s[g * 8];
    }
}

// ---------------------------------------------------------------------------
// Kernel 2: fused vec_dot (MFMA) + vec_norm + V^T vec-rows. grid 512 x 512.
// Wvec fragment loads hoisted out of the c-loop (c-invariant): 32 loads not 96.
// ---------------------------------------------------------------------------
__global__ __launch_bounds__(512) void vec_kernel(
    const float* __restrict__ x, const short* __restrict__ Wvecb,
    float* __restrict__ dotb, short* __restrict__ invb,
    float* __restrict__ normb, short* __restrict__ vtb)
{
    __shared__ short vb[3 * 16 * 264];
    const int tid = threadIdx.x;
    const int m0 = blockIdx.x * 16;
    const int b = m0 >> 11, n0 = m0 & 2047;

    #pragma unroll
    for (int p = 0; p < 6; p++) {
        int f4 = p * 512 + tid;
        int t = f4 / 192;
        int rem = f4 - t * 192;
        int c = rem >> 6, j4 = rem & 63;
        float4 v = *(const float4*)(x + (size_t)(m0 + t) * 1024 + 256 + c * 256 + j4 * 4);
        short4v s = { f2bf(v.x), f2bf(v.y), f2bf(v.z), f2bf(v.w) };
        *(short4v*)&vb[(c * 16 + t) * 264 + j4 * 4] = s;
    }
    __syncthreads();

    const int wave = tid >> 6, lane = tid & 63;
    const int col = lane & 15, quad = lane >> 4;
    const int j0 = wave * 32;

    f32x4 d1[3][2], d2[3][2];
    #pragma unroll
    for (int c = 0; c < 3; c++)
        #pragma unroll
        for (int nt = 0; nt < 2; nt++) {
            d1[c][nt] = (f32x4){0.f,0.f,0.f,0.f};
            d2[c][nt] = (f32x4){0.f,0.f,0.f,0.f};
        }

    #pragma unroll
    for (int kk = 0; kk < 8; kk++) {
        short8 w1[2], w2[2];
        #pragma unroll
        for (int nt = 0; nt < 2; nt++) {
            w1[nt] = *(const short8*)&Wvecb[(size_t)(j0 + nt * 16 + col) * 256 + kk * 32 + quad * 8];
            w2[nt] = *(const short8*)&Wvecb[(size_t)(256 + j0 + nt * 16 + col) * 256 + kk * 32 + quad * 8];
        }
        #pragma unroll
        for (int c = 0; c < 3; c++) {
            short8 xf = *(const short8*)&vb[(c * 16 + col) * 264 + kk * 32 + quad * 8];
            #pragma unroll
            for (int nt = 0; nt < 2; nt++) {
                d1[c][nt] = __builtin_amdgcn_mfma_f32_16x16x32_bf16(w1[nt], xf, d1[c][nt], 0, 0, 0);
                d2[c][nt] = __builtin_amdgcn_mfma_f32_16x16x32_bf16(w2[nt], xf, d2[c][nt], 0, 0, 0);
            }
        }
    }
    #pragma unroll
    for (int nt = 0; nt < 2; nt++) {
        f32x4 dac = d1[0][nt] * d2[0][nt] + d1[1][nt] * d2[1][nt] + d1[2][nt] * d2[2][nt];
        float4 o = { dac[0], dac[1], dac[2], dac[3] };
        *(float4*)&dotb[(size_t)(m0 + col) * 256 + j0 + nt * 16 + quad * 4] = o;
        short4v s = { f2bf(dac[0]), f2bf(dac[1]), f2bf(dac[2]), f2bf(dac[3]) };
        *(short4v*)&invb[(size_t)(m0 + col) * 512 + j0 + nt * 16 + quad * 4] = s;
    }

    const int j = tid & 255, tp = tid >> 8;
    const int h = j >> 5, d = j & 31;
    #pragma unroll
    for (int t8 = 0; t8 < 8; t8++) {
        int t = tp * 8 + t8;
        float v0 = bf2f(vb[(0 * 16 + t) * 264 + j]);
        float v1 = bf2f(vb[(1 * 16 + t) * 264 + j]);
        float v2 = bf2f(vb[(2 * 16 + t) * 264 + j]);
        float nm = sqrtf(v0 * v0 + v1 * v1 + v2 * v2);
        normb[(size_t)(m0 + t) * 256 + j] = nm;
        invb[(size_t)(m0 + t) * 512 + 256 + j] = f2bf(nm);
    }
    #pragma unroll
    for (int c = 0; c < 3; c++) {
        short8 s;
        #pragma unroll
        for (int t8 = 0; t8 < 8; t8++) s[t8] = vb[(c * 16 + tp * 8 + t8) * 264 + j];
        size_t row = ((size_t)(b * 8 + h) * 128 + 32 + c * 32 + d) * 2048 + n0 + tp * 8;
        *(short8*)(vtb + row) = s;
    }
}

// ---------------------------------------------------------------------------
// Kernel 3: MFMA flash attention. 32 queries/wave (2 m-strips), no-max softmax
// (exp2 domain), K/V staged in LDS, per-wave P buffers, 2 barriers/iter.
// grid 512 (bh x 16 q-tiles of 128), block 256 (4 waves x 32 q).
// ---------------------------------------------------------------------------
__global__ __launch_bounds__(256) void attn_kernel(
    const short* __restrict__ qb, const short* __restrict__ kb,
    const short* __restrict__ vtb,
    short* __restrict__ xob, short* __restrict__ ovb)
{
    __shared__ short Ks[64 * 40];          // 5.1 KB
    __shared__ short Vs[128 * 72];         // 18.4 KB
    __shared__ short Pl[4][2][16 * 40];    // 10.2 KB
    const int tid = threadIdx.x;
    const int wave = tid >> 6, lane = tid & 63;
    const int col = lane & 15, quad = lane >> 4;
    const int bh = blockIdx.x >> 4, qt = blockIdx.x & 15;
    const int m0 = qt * 128 + wave * 32;
    const int b = bh >> 3, h = bh & 7;

    const short* qbase = qb + (size_t)bh * NSEQ * HD;
    const short* kbase = kb + (size_t)bh * NSEQ * HD;
    const short* vbase = vtb + (size_t)bh * 128 * NSEQ;

    short8 qfrag[2];
    #pragma unroll
    for (int s = 0; s < 2; s++)
        qfrag[s] = *(const short8*)(qbase + (size_t)(m0 + s * 16 + col) * 32 + quad * 8);

    f32x4 o[2][8];
    #pragma unroll
    for (int s = 0; s < 2; s++)
        #pragma unroll
        for (int dt = 0; dt < 8; dt++) o[dt ? s : s][dt] = (f32x4){0.f,0.f,0.f,0.f};
    #pragma unroll
    for (int s = 0; s < 2; s++)
        #pragma unroll
        for (int dt = 0; dt < 8; dt++) o[s][dt] = (f32x4){0.f,0.f,0.f,0.f};
    float lrun[2] = {0.f, 0.f};

    const int kr = tid >> 2, kseg = tid & 3;
    for (int kt = 0; kt < 32; kt++) {
        __syncthreads();
        *(short8*)&Ks[kr * 40 + kseg * 8] =
            *(const short8*)(kbase + (size_t)(kt * 64 + kr) * 32 + kseg * 8);
        #pragma unroll
        for (int p = 0; p < 4; p++) {
            int i = p * 256 + tid;
            int r = i >> 3, seg = i & 7;
            *(short8*)&Vs[r * 72 + seg * 8] =
                *(const short8*)(vbase + (size_t)r * NSEQ + kt * 64 + seg * 8);
        }
        __syncthreads();

        short8 kf[4];
        #pragma unroll
        for (int nt = 0; nt < 4; nt++)
            kf[nt] = *(const short8*)&Ks[(nt * 16 + col) * 40 + quad * 8];

        #pragma unroll
        for (int s = 0; s < 2; s++) {
            f32x4 sc[4];
            #pragma unroll
            for (int nt = 0; nt < 4; nt++)
                sc[nt] = __builtin_amdgcn_mfma_f32_16x16x32_bf16(
                    kf[nt], qfrag[s], (f32x4){0.f,0.f,0.f,0.f}, 0, 0, 0);
            float rs = 0.f;
            short* pd = &Pl[wave][s][col * 40];
            #pragma unroll
            for (int nt = 0; nt < 4; nt++) {
                float p0 = exp2f(sc[nt][0]), p1 = exp2f(sc[nt][1]);
                float p2 = exp2f(sc[nt][2]), p3 = exp2f(sc[nt][3]);
                rs += (p0 + p1) + (p2 + p3);
                uint32_t w0 = (fbits(p0) >> 16) | (fbits(p1) & 0xFFFF0000u);
                uint32_t w1 = (fbits(p2) >> 16) | (fbits(p3) & 0xFFFF0000u);
                uint2 w = { w0, w1 };
                *(uint2*)(pd + nt * 16 + quad * 4) = w;
            }
            lrun[s] += rs;
        }

        #pragma unroll
        for (int c = 0; c < 2; c++) {
            short8 pa[2];
            #pragma unroll
            for (int s = 0; s < 2; s++)
                pa[s] = *(const short8*)&Pl[wave][s][col * 40 + c * 32 + quad * 8];
            #pragma unroll
            for (int dt = 0; dt < 8; dt++) {
                short8 vf = *(const short8*)&Vs[(dt * 16 + col) * 72 + c * 32 + quad * 8];
                #pragma unroll
                for (int s = 0; s < 2; s++)
                    o[s][dt] = __builtin_amdgcn_mfma_f32_16x16x32_bf16(vf, pa[s], o[s][dt], 0, 0, 0);
            }
        }
    }

    #pragma unroll
    for (int s = 0; s < 2; s++) {
        float l = lrun[s];
        l += __shfl_xor(l, 16);
        l += __shfl_xor(l, 32);
        float linv = 1.0f / l;

        size_t mg = (size_t)b * 2048 + m0 + s * 16 + col;
        short* xr = xob + mg * 256 + h * 32;
        #pragma unroll
        for (int dt = 0; dt < 2; dt++) {
            short4v sv = { f2bf(o[s][dt][0] * linv), f2bf(o[s][dt][1] * linv),
                           f2bf(o[s][dt][2] * linv), f2bf(o[s][dt][3] * linv) };
            *(short4v*)(xr + dt * 16 + quad * 4) = sv;
        }
        short* vr = ovb + mg * 768 + h * 32;
        #pragma unroll
        for (int dt = 2; dt < 8; dt++) {
            int c = (dt - 2) >> 1, d2 = ((dt - 2) & 1) * 16 + quad * 4;
            short4v sv = { f2bf(o[s][dt][0] * linv), f2bf(o[s][dt][1] * linv),
                           f2bf(o[s][dt][2] * linv), f2bf(o[s][dt][3] * linv) };
            *(short4v*)(vr + c * 256 + d2) = sv;
        }
    }
}

// ---------------------------------------------------------------------------
// Kernel 4: MFMA epilogue GEMM + fused combine. grid 512, block 256.
// ---------------------------------------------------------------------------
__global__ __launch_bounds__(256) void ogemm_kernel(
    const float* __restrict__ x, const short* __restrict__ xob,
    const short* __restrict__ invb,
    const float* __restrict__ dotb, const float* __restrict__ normb,
    const short* __restrict__ ovb,
    const short* __restrict__ Wob, const short* __restrict__ Wgb,
    const float* __restrict__ bo, const float* __restrict__ bg,
    float* __restrict__ out)
{
    __shared__ __align__(16) union {
        struct { short inv[16 * 520]; short xo[16 * 264]; } in;
        struct { short gate[16 * 264]; short o[16 * 776]; } ob;
    } u;
    const int tid = threadIdx.x;
    const int M0 = blockIdx.x * 16;

    #pragma unroll
    for (int l = 0; l < 4; l++) {
        int i = l * 256 + tid;
        int m = i >> 6, seg = i & 63;
        *(short8*)&u.in.inv[m * 520 + seg * 8] =
            *(const short8*)(invb + (size_t)(M0 + m) * 512 + seg * 8);
    }
    #pragma unroll
    for (int l = 0; l < 2; l++) {
        int i = l * 256 + tid;
        int m = i >> 5, seg = i & 31;
        *(short8*)&u.in.xo[m * 264 + seg * 8] =
            *(const short8*)(xob + (size_t)(M0 + m) * 256 + seg * 8);
    }
    __syncthreads();

    const int wave = tid >> 6, lane = tid & 63;
    const int col = lane & 15, quad = lane >> 4;

    f32x4 acc[16];
    #pragma unroll
    for (int nt = 0; nt < 16; nt++) acc[nt] = (f32x4){0.f,0.f,0.f,0.f};

    if (wave == 0) {
        #pragma unroll
        for (int kk = 0; kk < 16; kk++) {
            short8 xf = *(const short8*)&u.in.inv[col * 520 + kk * 32 + quad * 8];
            #pragma unroll
            for (int nt = 0; nt < 16; nt++) {
                short8 wf = *(const short8*)(Wgb + (size_t)(nt * 16 + col) * 512 + kk * 32 + quad * 8);
                acc[nt] = __builtin_amdgcn_mfma_f32_16x16x32_bf16(wf, xf, acc[nt], 0, 0, 0);
            }
        }
    } else {
        const short* Wb = Wob + (size_t)(wave - 1) * 256 * 256;
        #pragma unroll
        for (int kk = 0; kk < 8; kk++) {
            short8 xf = *(const short8*)&u.in.xo[col * 264 + kk * 32 + quad * 8];
            #pragma unroll
            for (int nt = 0; nt < 16; nt++) {
                short8 wf = *(const short8*)(Wb + (size_t)(nt * 16 + col) * 256 + kk * 32 + quad * 8);
                acc[nt] = __builtin_amdgcn_mfma_f32_16x16x32_bf16(wf, xf, acc[nt], 0, 0, 0);
            }
        }
    }
    __syncthreads();

    if (wave == 0) {
        #pragma unroll
        for (int nt = 0; nt < 16; nt++) {
            int ch = nt * 16 + quad * 4;
            float4 bi = *(const float4*)&bg[ch];
            short4v s = { f2bf(1.f / (1.f + __expf(-(acc[nt][0] + bi.x)))),
                          f2bf(1.f / (1.f + __expf(-(acc[nt][1] + bi.y)))),
                          f2bf(1.f / (1.f + __expf(-(acc[nt][2] + bi.z)))),
                          f2bf(1.f / (1.f + __expf(-(acc[nt][3] + bi.w)))) };
            *(short4v*)&u.ob.gate[col * 264 + ch] = s;
        }
    } else {
        #pragma unroll
        for (int nt = 0; nt < 16; nt++) {
            int ch = (wave - 1) * 256 + nt * 16 + quad * 4;
            float4 bi = *(const float4*)&bo[ch];
            short4v s = { f2bf(acc[nt][0] + bi.x), f2bf(acc[nt][1] + bi.y),
                          f2bf(acc[nt][2] + bi.z), f2bf(acc[nt][3] + bi.w) };
            *(short4v*)&u.ob.o[col * 776 + ch] = s;
        }
    }
    __syncthreads();

    #pragma unroll
    for (int l = 0; l < 16; l++) {
        int idx4 = l * 256 + tid;
        int m = idx4 >> 8;
        int j = (idx4 & 255) * 4;
        size_t mg = (size_t)(M0 + m);
        if (j < 256) {
            float4 dv = *(const float4*)(dotb + mg * 256 + j);
            float4 nv = *(const float4*)(normb + mg * 256 + j);
            short4v o1 = *(short4v*)&u.ob.o[m * 776 + j];
            short4v o2 = *(short4v*)&u.ob.o[m * 776 + 256 + j];
            short4v o3 = *(short4v*)&u.ob.o[m * 776 + 512 + j];
            float4 r;
            r.x = dv.x * bf2f(o1[0]) + nv.x * bf2f(o2[0]) + bf2f(o3[0]);
            r.y = dv.y * bf2f(o1[1]) + nv.y * bf2f(o2[1]) + bf2f(o3[1]);
            r.z = dv.z * bf2f(o1[2]) + nv.z * bf2f(o2[2]) + bf2f(o3[2]);
            r.w = dv.w * bf2f(o1[3]) + nv.w * bf2f(o2[3]) + bf2f(o3[3]);
            *(float4*)(out + mg * 1024 + j) = r;
        } else {
            int c = (j >> 8) - 1, jj = j & 255;
            short4v g4 = *(short4v*)&u.ob.gate[m * 264 + jj];
            short4v av4 = *(const short4v*)(ovb + mg * 768 + c * 256 + jj);
            float4 xv = *(const float4*)(x + mg * 1024 + 256 + c * 256 + jj);
            float4 r = { bf2f(g4[0]) * bf2f(av4[0]) + xv.x, bf2f(g4[1]) * bf2f(av4[1]) + xv.y,
                         bf2f(g4[2]) * bf2f(av4[2]) + xv.z, bf2f(g4[3]) * bf2f(av4[3]) + xv.w };
            *(float4*)(out + mg * 1024 + j) = r;
        }
    }
}

// ---------------------------------------------------------------------------
extern "C" void kernel_launch(void* const* d_in, const int* in_sizes, int n_in,
                              void* d_out, int out_size, void* d_ws, size_t ws_size,
                              hipStream_t stream)
{
    const float* x    = (const float*)d_in[0];
    const float* Wq   = (const float*)d_in[1];
    const float* bq   = (const float*)d_in[2];
    const float* Wk   = (const float*)d_in[3];
    const float* bk   = (const float*)d_in[4];
    const float* Wv   = (const float*)d_in[5];
    const float* bv   = (const float*)d_in[6];
    const float* Wvec = (const float*)d_in[7];
    const float* Wo   = (const float*)d_in[8];
    const float* bo   = (const float*)d_in[9];
    const float* Wg   = (const float*)d_in[10];
    const float* bg   = (const float*)d_in[11];
    const float* adp  = (const float*)d_in[12];
    const float* anp  = (const float*)d_in[13];
    float* out = (float*)d_out;

    float* ws    = (float*)d_ws;
    short* qbf   = (short*)ws;
    short* kbf   = (short*)(ws + 1048576);
    short* vtb   = (short*)(ws + 2097152);
    float* dotb  = ws + 6291456;
    float* normb = ws + 8388608;
    short* xob   = (short*)(ws + 10485760);
    short* ovb   = (short*)(ws + 11534336);
    short* invb  = (short*)(ws + 17825792);
    short* Wqkvb = (short*)(ws + 19922944);
    float* bqkvs = ws + 20021248;
    short* Wvecb = (short*)(ws + 20022016);
    short* Wob   = (short*)(ws + 20087552);
    short* Wgb   = (short*)(ws + 20185856);

    wcvt_kernel<<<2560, 256, 0, stream>>>(Wq, Wk, Wv, Wvec, Wo, Wg, bq, bk, bv,
                                          adp, anp, Wqkvb, Wvecb, Wob, Wgb, bqkvs);
    qkv_kernel<<<256, 256, 0, stream>>>(x, Wqkvb, bqkvs, qbf, kbf, vtb);
    vec_kernel<<<512, 512, 0, stream>>>(x, Wvecb, dotb, invb, normb, vtb);
    attn_kernel<<<512, 256, 0, stream>>>(qbf, kbf, vtb, xob, ovb);
    ogemm_kernel<<<512, 256, 0, stream>>>(x, xob, invb, dotb, normb, ovb,
                                          Wob, Wgb, bo, bg, out);
}